// Round 11
// baseline (10412.631 us; speedup 1.0000x reference)
//
#include <hip/hip_runtime.h>
#include <hip/hip_cooperative_groups.h>
#include <math.h>

// Problem constants (match reference)
#define DT_     0.1f
#define TAU_M_  10.0f
#define TAU_S_  5.0f
#define NP_     8      // P populations
#define NN_     2048   // N neurons
#define NE_     16     // E edges
#define NB_     4      // B batch
#define NT_     128    // T steps
#define NEDGE_  17     // 16 recurrent + 1 input projection

// Weight residency per wave (wave owns one output column j):
//   e 0..7   -> VGPR (8 edges x 16 packed-u32 regs = 128 VGPR)
//   e 8..11  -> LDS  (4 edges x 8 waves x 4 KB = 128 KB)
//   e 12..16 -> streamed from L2/L3 each step (41.9 MB/step chip-wide)
#define NVGPR_E   8
#define NLDS_E    4
#define NSTREAM_E 5

typedef unsigned int u32;
typedef __attribute__((ext_vector_type(2))) _Float16 half2v;

namespace cg = cooperative_groups;

__device__ __forceinline__ float sigmoidf_(float x) {
  return 1.0f / (1.0f + expf(-x));
}

__device__ __forceinline__ float dot2_(float acc, u32 p, u32 w) {
#if __has_builtin(__builtin_amdgcn_fdot2)
  return __builtin_amdgcn_fdot2(__builtin_bit_cast(half2v, p),
                                __builtin_bit_cast(half2v, w), acc, false);
#else
  half2v hp = __builtin_bit_cast(half2v, p);
  half2v hw = __builtin_bit_cast(half2v, w);
  return acc + (float)hp[0] * (float)hw[0] + (float)hp[1] * (float)hw[1];
#endif
}

// ---- Setup 1: transpose weights to Wt[e][j][i2] packed fp16 (i,i+1) pairs.
__global__ __launch_bounds__(256) void k_transpose(
    const float* __restrict__ W, const float* __restrict__ W_in,
    u32* __restrict__ Wt32) {
  const int e  = blockIdx.x;          // 0..16
  const int jt = blockIdx.y;          // 0..31
  const int it = blockIdx.z;          // 0..31
  const float* Wsrc = (e == 16) ? W_in : (W + (size_t)e * NN_ * NN_);
  __shared__ float tile[64][65];
  const int i0 = it * 64, j0 = jt * 64;
  for (int k = threadIdx.x; k < 4096; k += 256) {
    int r = k >> 6, c = k & 63;
    tile[r][c] = Wsrc[(size_t)(i0 + r) * NN_ + j0 + c];
  }
  __syncthreads();
  for (int k = threadIdx.x; k < 2048; k += 256) {
    int jr = k >> 5, ip = k & 31;
    half2v h;
    h[0] = (_Float16)tile[2 * ip][jr];
    h[1] = (_Float16)tile[2 * ip + 1][jr];
    Wt32[((size_t)e * NN_ + (j0 + jr)) * 1024 + (i0 >> 1) + ip] =
        __builtin_bit_cast(u32, h);
  }
}

// ---- Setup 2: input-population rates for all (t,b), packed fp16 pairs.
__global__ __launch_bounds__(256) void k_inrate(
    const float* __restrict__ t_seq, u32* __restrict__ inp) {
  const int t = blockIdx.x >> 2, b = blockIdx.x & 3;
  const float tt = t_seq[b * NT_ + t];
  const float base = 0.062831853071795864f * tt;  // 2*pi*t/100
  for (int p2 = threadIdx.x; p2 < 1024; p2 += 256) {
    int i = 2 * p2;
    float ph0 = (float)i * (6.2831853071795864f / (float)NN_);
    float ph1 = (float)(i + 1) * (6.2831853071795864f / (float)NN_);
    half2v h;
    h[0] = (_Float16)(0.5f * (1.0f + sinf(base + ph0)));
    h[1] = (_Float16)(0.5f * (1.0f + sinf(base + ph1)));
    inp[(size_t)(t * NB_ + b) * 1024 + p2] = __builtin_bit_cast(u32, h);
  }
}

// ---- Setup 3: rates_0 = sigmoid(v0) as fp16 [p][b][n]
__global__ __launch_bounds__(256) void k_rates0(
    const float* __restrict__ v0, _Float16* __restrict__ rh0) {
  int idx = blockIdx.x * 256 + threadIdx.x;   // 0..65535
  rh0[idx] = (_Float16)sigmoidf_(v0[idx]);
}

// One edge, with COMPILE-TIME edge index E_ (macro-expanded 17x below).
// All register-array indices are constexpr -> no scratch allocation possible.
#define EDGE(E_) {                                                            \
  constexpr int E = (E_);                                                     \
  bool do_stage;                                                              \
  if (E == 0 || E == 16) do_stage = true;                                     \
  else do_stage = (sg[E] != sg[(E > 0) ? (E - 1) : 0]);                       \
  if (do_stage) {                                                             \
    __syncthreads();                                                          \
    _Pragma("unroll")                                                         \
    for (int k = 0; k < 8; ++k)                                               \
      pairs_u[sb * 1024 + soff + lane + 64 * k] = streg[k];                   \
    __syncthreads();                                                          \
  }                                                                           \
  if constexpr (E < 16) {                                                     \
    bool next_stage = (E + 1 == 16) ||                                        \
                      (sg[(E + 1 < 16) ? (E + 1) : 0] != sg[E]);              \
    if (next_stage) {                                                         \
      const u32* np = (E + 1 == 16)                                           \
          ? (inp + (size_t)(t * NB_ + sb) * 1024 + soff)                      \
          : (rcur + ((size_t)(sg[(E + 1 < 16) ? (E + 1) : 0] * NB_ + sb))     \
                    * 1024 + soff);                                           \
      _Pragma("unroll")                                                       \
      for (int k = 0; k < 8; ++k) streg[k] = np[lane + 64 * k];               \
    }                                                                         \
  }                                                                           \
  float acc0 = 0.0f, acc1 = 0.0f, acc2 = 0.0f, acc3 = 0.0f;                   \
  _Pragma("unroll")                                                           \
  for (int k = 0; k < 16; ++k) {                                              \
    const int idx = lane + 64 * k;                                            \
    u32 w;                                                                    \
    if constexpr (E < NVGPR_E)                                                \
      w = wvreg[(E < NVGPR_E) ? E : 0][k];                                    \
    else if constexpr (E < NVGPR_E + NLDS_E)                                  \
      w = lds_w[(E >= NVGPR_E && E < NVGPR_E + NLDS_E) ? (E - NVGPR_E) : 0]   \
               [wv][idx];                                                     \
    else                                                                      \
      w = wst[(E >= NVGPR_E + NLDS_E) ? (E - NVGPR_E - NLDS_E) : 0][idx];     \
    acc0 = dot2_(acc0, pairs_u[idx], w);                                      \
    acc1 = dot2_(acc1, pairs_u[1024 + idx], w);                               \
    acc2 = dot2_(acc2, pairs_u[2048 + idx], w);                               \
    acc3 = dot2_(acc3, pairs_u[3072 + idx], w);                               \
  }                                                                           \
  float t0 = acc0 + __shfl_xor(acc0, 1, 64);                                  \
  float t1 = acc1 + __shfl_xor(acc1, 1, 64);                                  \
  float t2 = acc2 + __shfl_xor(acc2, 1, 64);                                  \
  float t3 = acc3 + __shfl_xor(acc3, 1, 64);                                  \
  float u0 = (lane & 1) ? t1 : t0;                                            \
  float u2 = (lane & 1) ? t3 : t2;                                            \
  u0 = u0 + __shfl_xor(u0, 2, 64);                                            \
  u2 = u2 + __shfl_xor(u2, 2, 64);                                            \
  float r = (lane & 2) ? u2 : u0;                                             \
  r += __shfl_xor(r, 4, 64);                                                  \
  r += __shfl_xor(r, 8, 64);                                                  \
  r += __shfl_xor(r, 16, 64);                                                 \
  r += __shfl_xor(r, 32, 64);                                                 \
  if constexpr (E < NE_) {                                                    \
    if ((lane >> 2) == E) s_reg += DT_ * (r - s_reg * (1.0f / TAU_S_));       \
  } else {                                                                    \
    if (lane < 4) si_reg += DT_ * (r - si_reg * (1.0f / TAU_S_));             \
  }                                                                           \
}

// ---- Persistent cooperative simulation kernel ----
// 256 blocks x 512 threads = 1 block/CU (LDS 144 KB forces it; grid == CU
// count so co-residency guaranteed). launch_bounds(512,2): 2 waves/EU ->
// VGPR cap 256. wvreg[8][16]=128 regs, statically indexed via EDGE() macro.
__global__ __launch_bounds__(512, 2) void k_sim(
    const u32* __restrict__ Wt32, const u32* __restrict__ inp,
    const int* __restrict__ srcg, const int* __restrict__ tgtg,
    const float* __restrict__ v0, const float* __restrict__ s0,
    const float* __restrict__ s_in0,
    u32* __restrict__ rb0, u32* __restrict__ rb1,
    float* __restrict__ errw, float* __restrict__ out) {
  const int tid  = threadIdx.x;
  const int lane = tid & 63;
  const int wv   = tid >> 6;                 // 0..7
  const int j    = blockIdx.x * 8 + wv;      // owned column
  const int sb   = wv >> 1;                  // staging batch (2 waves/batch)
  const int soff = (wv & 1) * 512;           // staging half offset

  __shared__ u32 lds_w[NLDS_E][8][1024];     // 128 KB
  __shared__ u32 pairs_u[NB_ * 1024];        // 16 KB: [b][i2] pre pairs

  // graph arrays -> SGPRs (uniform by construction)
  int sg[NE_], tg[NE_];
#pragma unroll
  for (int e = 0; e < NE_; ++e) {
    sg[e] = __builtin_amdgcn_readfirstlane(srcg[e]);
    tg[e] = __builtin_amdgcn_readfirstlane(tgtg[e]);
  }

  // --- resident weights ---
  u32 wvreg[NVGPR_E][16];
#pragma unroll
  for (int e = 0; e < NVGPR_E; ++e) {
    const u32* wp = Wt32 + ((size_t)e * NN_ + j) * 1024;
#pragma unroll
    for (int k = 0; k < 16; ++k) wvreg[e][k] = wp[lane + 64 * k];
  }
#pragma unroll
  for (int e2 = 0; e2 < NLDS_E; ++e2) {
    const u32* wp = Wt32 + ((size_t)(NVGPR_E + e2) * NN_ + j) * 1024;
#pragma unroll
    for (int k = 0; k < 16; ++k)
      lds_w[e2][wv][lane + 64 * k] = wp[lane + 64 * k];
  }
  const u32* wst[NSTREAM_E];
#pragma unroll
  for (int e3 = 0; e3 < NSTREAM_E; ++e3)
    wst[e3] = Wt32 + ((size_t)(NVGPR_E + NLDS_E + e3) * NN_ + j) * 1024;

  // --- state registers ---
  float s_reg  = s0[((size_t)(lane >> 2) * NB_ + (lane & 3)) * NN_ + j];
  float si_reg = (lane < 4) ? s_in0[lane * NN_ + j] : 0.0f;
  float v_reg  = (lane < 32)
      ? v0[((size_t)(lane >> 2) * NB_ + (lane & 3)) * NN_ + j] : 0.0f;
  float err_acc = 0.0f;

  cg::grid_group gg = cg::this_grid();
  u32 streg[8];

  for (int t = 0; t < NT_; ++t) {
    const u32* rcur = (t & 1) ? rb1 : rb0;
    u32* rnext = (t & 1) ? rb0 : rb1;
    _Float16* rnh = (_Float16*)rnext;

    // prologue prefetch for E=0
    {
      const u32* rp = rcur + ((size_t)(sg[0] * NB_ + sb)) * 1024 + soff;
#pragma unroll
      for (int k = 0; k < 8; ++k) streg[k] = rp[lane + 64 * k];
    }

    EDGE(0);  EDGE(1);  EDGE(2);  EDGE(3);  EDGE(4);  EDGE(5);
    EDGE(6);  EDGE(7);  EDGE(8);  EDGE(9);  EDGE(10); EDGE(11);
    EDGE(12); EDGE(13); EDGE(14); EDGE(15); EDGE(16);

    // ---- v-phase: lanes 0..31 own (p = lane>>2, b = lane&3) ----
    {
      const int p = lane >> 2, b = lane & 3;
      float S = 0.0f;
#pragma unroll
      for (int e = 0; e < NE_; ++e) {
        float se = __shfl(s_reg, e * 4 + b, 64);
        if (tg[e] == p) S += se;
      }
      float sival = __shfl(si_reg, b, 64);
      if (p == 0) S += sival;
      float vv = v_reg;
      float I  = S * (1.0f - vv);            // E_REV=1, G_MAX=1
      float dv = (-vv - S * vv + I) * (1.0f / TAU_M_);
      float vn = vv + DT_ * dv;
      v_reg = vn;
      float rr = sigmoidf_(vn);
      if (lane < 32) {
        rnh[((size_t)(p * NB_ + b)) * NN_ + j] = (_Float16)rr;
        out[(((size_t)b * NT_ + t) * NP_ + p) * NN_ + j] = rr;
      }
      float ea = (lane < 32) ? fabsf(dv) : 0.0f;
#pragma unroll
      for (int off = 1; off < 64; off <<= 1) ea += __shfl_xor(ea, off, 64);
      err_acc += ea;
    }

    gg.sync();
  }

  if (lane == 0) errw[j] = err_acc;
}

// ---- err finalize: separate kernel, deterministic fixed-order reduce ----
__global__ __launch_bounds__(256) void k_err(
    const float* __restrict__ errw, float* __restrict__ out_err) {
  __shared__ float red[256];
  float s = 0.0f;
  for (int k = threadIdx.x; k < 2048; k += 256) s += errw[k];
  red[threadIdx.x] = s;
  __syncthreads();
  for (int w = 128; w > 0; w >>= 1) {
    if (threadIdx.x < w) red[threadIdx.x] += red[threadIdx.x + w];
    __syncthreads();
  }
  if (threadIdx.x == 0)
    *out_err = red[0] * (DT_ / (float)(NP_ * NB_ * NN_));
}

extern "C" void kernel_launch(void* const* d_in, const int* in_sizes, int n_in,
                              void* d_out, int out_size, void* d_ws, size_t ws_size,
                              hipStream_t stream) {
  const float* t_seq = (const float*)d_in[0];   // [B,T]
  const float* W     = (const float*)d_in[1];   // [E,N,N]
  const float* W_in  = (const float*)d_in[2];   // [N,N]
  const float* v0    = (const float*)d_in[3];   // [P,B,N]
  const float* s0    = (const float*)d_in[4];   // [E,B,N]
  const float* s_in0 = (const float*)d_in[5];   // [B,N]
  const int*   srcp  = (const int*)d_in[6];     // [E]
  const int*   tgtp  = (const int*)d_in[7];     // [E]
  float* outp = (float*)d_out;                  // [B,T,P,N] + err

  // Workspace layout (~145 MB; ws proven >= 148 MB by R2-R7 fp16 path)
  u32* Wt32 = (u32*)d_ws;                                  // 17*2048*1024
  u32* inp  = Wt32 + (size_t)NEDGE_ * NN_ * 1024;          // 128*4*1024
  u32* rb0  = inp + (size_t)NT_ * NB_ * 1024;              // 8*4*1024
  u32* rb1  = rb0 + (size_t)NP_ * NB_ * 1024;
  float* errw = (float*)(rb1 + (size_t)NP_ * NB_ * 1024);  // 2048 floats

  hipLaunchKernelGGL(k_transpose, dim3(NEDGE_, 32, 32), dim3(256), 0, stream,
                     W, W_in, Wt32);
  hipLaunchKernelGGL(k_inrate, dim3(NT_ * NB_), dim3(256), 0, stream,
                     t_seq, inp);
  hipLaunchKernelGGL(k_rates0, dim3(256), dim3(256), 0, stream,
                     v0, (_Float16*)rb0);

  void* kargs[] = {(void*)&Wt32, (void*)&inp, (void*)&srcp, (void*)&tgtp,
                   (void*)&v0, (void*)&s0, (void*)&s_in0,
                   (void*)&rb0, (void*)&rb1, (void*)&errw, (void*)&outp};
  hipLaunchCooperativeKernel((const void*)k_sim, dim3(256), dim3(512),
                             kargs, 0, stream);

  hipLaunchKernelGGL(k_err, dim3(1), dim3(256), 0, stream,
                     errw, outp + (size_t)NB_ * NT_ * NP_ * NN_);
}

// Round 12
// 3675.730 us; speedup vs baseline: 2.8328x; 2.8328x over previous
//
#include <hip/hip_runtime.h>
#include <math.h>

// Problem constants (match reference)
#define DT_     0.1f
#define TAU_M_  10.0f
#define TAU_S_  5.0f
#define NP_     8      // P populations
#define NN_     2048   // N neurons
#define NE_     16     // E edges
#define NB_     4      // B batch
#define NT_     128    // T steps
#define NEDGE_  17     // 16 recurrent + 1 input projection

typedef unsigned int u32;
typedef __attribute__((ext_vector_type(2))) _Float16 half2v;

__device__ __forceinline__ float sigmoidf_(float x) {
  return 1.0f / (1.0f + expf(-x));
}

__device__ __forceinline__ float dot2_(float acc, u32 p, u32 w) {
#if __has_builtin(__builtin_amdgcn_fdot2)
  return __builtin_amdgcn_fdot2(__builtin_bit_cast(half2v, p),
                                __builtin_bit_cast(half2v, w), acc, false);
#else
  half2v hp = __builtin_bit_cast(half2v, p);
  half2v hw = __builtin_bit_cast(half2v, w);
  return acc + (float)hp[0] * (float)hw[0] + (float)hp[1] * (float)hw[1];
#endif
}

// ---- Setup 1: transpose weights to Wt[e][j][i2] packed fp16 (i,i+1) pairs.
__global__ __launch_bounds__(256) void k_transpose(
    const float* __restrict__ W, const float* __restrict__ W_in,
    u32* __restrict__ Wt32) {
  const int e  = blockIdx.x;          // 0..16
  const int jt = blockIdx.y;          // 0..31
  const int it = blockIdx.z;          // 0..31
  const float* Wsrc = (e == 16) ? W_in : (W + (size_t)e * NN_ * NN_);
  __shared__ float tile[64][65];
  const int i0 = it * 64, j0 = jt * 64;
  for (int k = threadIdx.x; k < 4096; k += 256) {
    int r = k >> 6, c = k & 63;
    tile[r][c] = Wsrc[(size_t)(i0 + r) * NN_ + j0 + c];
  }
  __syncthreads();
  for (int k = threadIdx.x; k < 2048; k += 256) {
    int jr = k >> 5, ip = k & 31;
    half2v h;
    h[0] = (_Float16)tile[2 * ip][jr];
    h[1] = (_Float16)tile[2 * ip + 1][jr];
    Wt32[((size_t)e * NN_ + (j0 + jr)) * 1024 + (i0 >> 1) + ip] =
        __builtin_bit_cast(u32, h);
  }
}

// ---- Setup 2: input-population rates for all (t,b), packed fp16 pairs.
__global__ __launch_bounds__(256) void k_inrate(
    const float* __restrict__ t_seq, u32* __restrict__ inp) {
  const int t = blockIdx.x >> 2, b = blockIdx.x & 3;
  const float tt = t_seq[b * NT_ + t];
  const float base = 0.062831853071795864f * tt;  // 2*pi*t/100
  for (int p2 = threadIdx.x; p2 < 1024; p2 += 256) {
    int i = 2 * p2;
    float ph0 = (float)i * (6.2831853071795864f / (float)NN_);
    float ph1 = (float)(i + 1) * (6.2831853071795864f / (float)NN_);
    half2v h;
    h[0] = (_Float16)(0.5f * (1.0f + sinf(base + ph0)));
    h[1] = (_Float16)(0.5f * (1.0f + sinf(base + ph1)));
    inp[(size_t)(t * NB_ + b) * 1024 + p2] = __builtin_bit_cast(u32, h);
  }
}

// ---- Setup 3: rates_0 = sigmoid(v0) as fp16 [p][b][n]
__global__ __launch_bounds__(256) void k_rates0(
    const float* __restrict__ v0, _Float16* __restrict__ rh0) {
  int idx = blockIdx.x * 256 + threadIdx.x;   // 0..65535
  rh0[idx] = (_Float16)sigmoidf_(v0[idx]);
}

// ---- Setup 4: copy state to workspace, zero err accumulator.
__global__ __launch_bounds__(256) void k_init(
    const float* __restrict__ v0, const float* __restrict__ s0,
    const float* __restrict__ s_in0,
    float* __restrict__ vg, float* __restrict__ sg,
    float* __restrict__ sig, float* __restrict__ errw) {
  int idx = blockIdx.x * 256 + threadIdx.x;
  if (idx < NE_ * NB_ * NN_) sg[idx] = s0[idx];
  if (idx < NP_ * NB_ * NN_) vg[idx] = v0[idx];
  if (idx < NB_ * NN_) sig[idx] = s_in0[idx];
  if (idx < NN_) errw[idx] = 0.0f;
}

// ---- Per-step fused kernel ----
// 512 blocks x 256 threads; wave wv owns column j = blockIdx.x*4 + wv.
// All 17 edges streamed from cache/HBM as contiguous uint4 per column.
// s-update and v-update are wave-local (layout verified in R9-R11).
__global__ __launch_bounds__(256) void k_step(
    const u32* __restrict__ Wt32, const u32* __restrict__ inp,
    const int* __restrict__ srcg, const int* __restrict__ tgtg,
    const u32* __restrict__ rcur, u32* __restrict__ rnext,
    float* __restrict__ sg_, float* __restrict__ sig_,
    float* __restrict__ vg_, float* __restrict__ errw,
    float* __restrict__ out, int t) {
  const int tid  = threadIdx.x;
  const int lane = tid & 63;
  const int wv   = tid >> 6;             // 0..3
  const int j    = blockIdx.x * 4 + wv;  // owned column

  __shared__ u32 pairs_u[NB_ * 1024];    // 16 KB: [b][i2] pre pairs

  // state: lane owns s(e=lane>>2, b=lane&3); si on lanes 0..3
  float s_reg  = sg_[(size_t)lane * NN_ + j];
  float si_reg = (lane < 4) ? sig_[(size_t)lane * NN_ + j] : 0.0f;

  u32 streg[16];
  // prologue prefetch: edge 0 source pop (16 u32 per thread, contiguous)
  {
    const u32* rp = rcur + (size_t)srcg[0] * 4096 + tid * 16;
#pragma unroll
    for (int c = 0; c < 4; ++c) {
      uint4 q = *(const uint4*)(rp + c * 4);
      streg[c * 4 + 0] = q.x; streg[c * 4 + 1] = q.y;
      streg[c * 4 + 2] = q.z; streg[c * 4 + 3] = q.w;
    }
  }

  for (int E = 0; E < NEDGE_; ++E) {
    // ---- stage prefetched pre-pairs to LDS (block-uniform) ----
    bool do_stage = (E == 0) || (E == 16) || (srcg[E] != srcg[E - 1]);
    if (do_stage) {
      __syncthreads();
#pragma unroll
      for (int c = 0; c < 4; ++c) {
        uint4 q = {streg[c * 4 + 0], streg[c * 4 + 1],
                   streg[c * 4 + 2], streg[c * 4 + 3]};
        *(uint4*)(&pairs_u[tid * 16 + c * 4]) = q;
      }
      __syncthreads();
    }
    // ---- prefetch next staged edge (before heavy compute) ----
    if (E < 16) {
      bool next_stage = (E + 1 == 16) || (srcg[E + 1] != srcg[E]);
      if (next_stage) {
        const u32* np = (E + 1 == 16)
            ? (inp + (size_t)t * NB_ * 1024 + tid * 16)
            : (rcur + (size_t)srcg[E + 1] * 4096 + tid * 16);
#pragma unroll
        for (int c = 0; c < 4; ++c) {
          uint4 q = *(const uint4*)(np + c * 4);
          streg[c * 4 + 0] = q.x; streg[c * 4 + 1] = q.y;
          streg[c * 4 + 2] = q.z; streg[c * 4 + 3] = q.w;
        }
      }
    }

    // ---- dot partials: lane covers i2 = c*256 + lane*4 + m ----
    const u32* wp = Wt32 + ((size_t)E * NN_ + j) * 1024;
    float acc0 = 0.0f, acc1 = 0.0f, acc2 = 0.0f, acc3 = 0.0f;
#pragma unroll
    for (int c = 0; c < 4; ++c) {
      const int base = c * 256 + lane * 4;
      uint4 w = *(const uint4*)(wp + base);
      uint4 p0 = *(const uint4*)(&pairs_u[base]);
      uint4 p1 = *(const uint4*)(&pairs_u[1024 + base]);
      uint4 p2 = *(const uint4*)(&pairs_u[2048 + base]);
      uint4 p3 = *(const uint4*)(&pairs_u[3072 + base]);
      acc0 = dot2_(dot2_(dot2_(dot2_(acc0, p0.x, w.x), p0.y, w.y), p0.z, w.z), p0.w, w.w);
      acc1 = dot2_(dot2_(dot2_(dot2_(acc1, p1.x, w.x), p1.y, w.y), p1.z, w.z), p1.w, w.w);
      acc2 = dot2_(dot2_(dot2_(dot2_(acc2, p2.x, w.x), p2.y, w.y), p2.z, w.z), p2.w, w.w);
      acc3 = dot2_(dot2_(dot2_(dot2_(acc3, p3.x, w.x), p3.y, w.y), p3.z, w.z), p3.w, w.w);
    }

    // ---- transpose-reduce: every lane ends with full sum for b = lane&3 ----
    float t0 = acc0 + __shfl_xor(acc0, 1, 64);
    float t1 = acc1 + __shfl_xor(acc1, 1, 64);
    float t2 = acc2 + __shfl_xor(acc2, 1, 64);
    float t3 = acc3 + __shfl_xor(acc3, 1, 64);
    float u0 = (lane & 1) ? t1 : t0;
    float u2 = (lane & 1) ? t3 : t2;
    u0 = u0 + __shfl_xor(u0, 2, 64);
    u2 = u2 + __shfl_xor(u2, 2, 64);
    float r = (lane & 2) ? u2 : u0;
    r += __shfl_xor(r, 4, 64);
    r += __shfl_xor(r, 8, 64);
    r += __shfl_xor(r, 16, 64);
    r += __shfl_xor(r, 32, 64);

    // ---- s update on owning lanes ----
    if (E < NE_) {
      if ((lane >> 2) == E) s_reg += DT_ * (r - s_reg * (1.0f / TAU_S_));
    } else {
      if (lane < 4) si_reg += DT_ * (r - si_reg * (1.0f / TAU_S_));
    }
  }

  // ---- write back synapse state ----
  sg_[(size_t)lane * NN_ + j] = s_reg;
  if (lane < 4) sig_[(size_t)lane * NN_ + j] = si_reg;

  // ---- v-phase: lanes 0..31 own (p = lane>>2, b = lane&3) ----
  {
    const int p = lane >> 2, b = lane & 3;
    float S = 0.0f;
#pragma unroll
    for (int e = 0; e < NE_; ++e) {
      float se = __shfl(s_reg, e * 4 + b, 64);
      if (tgtg[e] == p) S += se;
    }
    float sival = __shfl(si_reg, b, 64);
    if (p == 0) S += sival;

    float vv = (lane < 32) ? vg_[(size_t)lane * NN_ + j] : 0.0f;
    float I  = S * (1.0f - vv);            // E_REV=1, G_MAX=1
    float dv = (-vv - S * vv + I) * (1.0f / TAU_M_);
    float vn = vv + DT_ * dv;
    float rr = sigmoidf_(vn);
    if (lane < 32) {
      vg_[(size_t)lane * NN_ + j] = vn;
      ((_Float16*)rnext)[(size_t)lane * NN_ + j] = (_Float16)rr;
      out[(((size_t)b * NT_ + t) * NP_ + p) * NN_ + j] = rr;
    }
    float ea = (lane < 32) ? fabsf(dv) : 0.0f;
#pragma unroll
    for (int off = 1; off < 64; off <<= 1) ea += __shfl_xor(ea, off, 64);
    if (lane == 0) errw[j] += ea;   // unique writer; deterministic order
  }
}

// ---- err finalize: deterministic fixed-order reduce ----
__global__ __launch_bounds__(256) void k_err(
    const float* __restrict__ errw, float* __restrict__ out_err) {
  __shared__ float red[256];
  float s = 0.0f;
  for (int k = threadIdx.x; k < NN_; k += 256) s += errw[k];
  red[threadIdx.x] = s;
  __syncthreads();
  for (int w = 128; w > 0; w >>= 1) {
    if (threadIdx.x < w) red[threadIdx.x] += red[threadIdx.x + w];
    __syncthreads();
  }
  if (threadIdx.x == 0)
    *out_err = red[0] * (DT_ / (float)(NP_ * NB_ * NN_));
}

extern "C" void kernel_launch(void* const* d_in, const int* in_sizes, int n_in,
                              void* d_out, int out_size, void* d_ws, size_t ws_size,
                              hipStream_t stream) {
  const float* t_seq = (const float*)d_in[0];   // [B,T]
  const float* W     = (const float*)d_in[1];   // [E,N,N]
  const float* W_in  = (const float*)d_in[2];   // [N,N]
  const float* v0    = (const float*)d_in[3];   // [P,B,N]
  const float* s0    = (const float*)d_in[4];   // [E,B,N]
  const float* s_in0 = (const float*)d_in[5];   // [B,N]
  const int*   srcp  = (const int*)d_in[6];     // [E]
  const int*   tgtp  = (const int*)d_in[7];     // [E]
  float* outp = (float*)d_out;                  // [B,T,P,N] + err

  // Workspace (~145 MB; ws >= 148 MB proven by R2-R7 fp16 path)
  u32* Wt32 = (u32*)d_ws;                                  // 17*2048*1024
  u32* inp  = Wt32 + (size_t)NEDGE_ * NN_ * 1024;          // 128*4*1024
  u32* rb0  = inp + (size_t)NT_ * NB_ * 1024;              // 8*4*1024
  u32* rb1  = rb0 + (size_t)NP_ * NB_ * 1024;
  float* sg   = (float*)(rb1 + (size_t)NP_ * NB_ * 1024);  // 16*4*2048
  float* vg   = sg + (size_t)NE_ * NB_ * NN_;              // 8*4*2048
  float* sig  = vg + (size_t)NP_ * NB_ * NN_;              // 4*2048
  float* errw = sig + (size_t)NB_ * NN_;                   // 2048

  hipLaunchKernelGGL(k_transpose, dim3(NEDGE_, 32, 32), dim3(256), 0, stream,
                     W, W_in, Wt32);
  hipLaunchKernelGGL(k_inrate, dim3(NT_ * NB_), dim3(256), 0, stream,
                     t_seq, inp);
  hipLaunchKernelGGL(k_rates0, dim3(256), dim3(256), 0, stream,
                     v0, (_Float16*)rb0);
  hipLaunchKernelGGL(k_init, dim3(512), dim3(256), 0, stream,
                     v0, s0, s_in0, vg, sg, sig, errw);

  u32* rb[2] = {rb0, rb1};
  for (int t = 0; t < NT_; ++t) {
    hipLaunchKernelGGL(k_step, dim3(512), dim3(256), 0, stream,
                       Wt32, inp, srcp, tgtp,
                       rb[t & 1], rb[(t + 1) & 1],
                       sg, sig, vg, errw, outp, t);
  }

  hipLaunchKernelGGL(k_err, dim3(1), dim3(256), 0, stream,
                     errw, outp + (size_t)NB_ * NT_ * NP_ * NN_);
}